// Round 6
// baseline (522.418 us; speedup 1.0000x reference)
//
#include <hip/hip_runtime.h>
#include <hip/hip_fp16.h>
#include <math.h>

#define N_NODES 50000
#define N_EDGES 800000
#define N_TOT   850000   // E + N self-loops
#define EPS_BN  1e-5f
#define GAT_SLOPE 0.2f
#define ACT_SLOPE 0.01f
#define SCAN_T   1024
#define N_TILES  ((N_NODES + SCAN_T - 1) / SCAN_T)   // 49

typedef _Float16 half8_t __attribute__((ext_vector_type(8)));
typedef _Float16 half4_t __attribute__((ext_vector_type(4)));
typedef float    f32x4   __attribute__((ext_vector_type(4)));

__device__ __forceinline__ float wred_max(float x) {
#pragma unroll
    for (int m = 32; m; m >>= 1) x = fmaxf(x, __shfl_xor(x, m, 64));
    return x;
}
__device__ __forceinline__ float wred_sum(float x) {
#pragma unroll
    for (int m = 32; m; m >>= 1) x += __shfl_xor(x, m, 64);
    return x;
}

__device__ __forceinline__ void store_val(float* p, float v) { *p = v; }
__device__ __forceinline__ void store_val(_Float16* p, float v) { *p = (_Float16)v; }

// ---- transpose + fp16-cast of W[K x C] -> Wt[C x K] ----
template<int K, int C>
__global__ void wcast_t(const float* __restrict__ W, _Float16* __restrict__ wt) {
    int i = blockIdx.x * 256 + threadIdx.x;
    if (i >= K * C) return;
    int k = i / C, c = i - k * C;          // coalesced read of W
    wt[(size_t)c * K + k] = (_Float16)W[i];
}

// ---- MFMA GEMM: out[n x C] = act(bn(x))[n x K] @ W[K x C] (+bias) ----
// 256 thr = 4 waves; 64 rows/block. Wave -> 64-col group (w % (C/64)), loops
// over RT=C/64 row-tiles; B-frags loaded once per k0 and reused across RT
// tiles (4*RT independent MFMAs per step). Optional fused BN+LeakyReLU on
// input during staging. If DOTS: epilogue computes e=h.a_s, f=h.a_d via
// 16-lane shfl reduce + LDS accumulation (replaces node_dots kernel).
// Layouts (verified m89/m120): A[m=lane&15][k=quad*8+j],
// B[k=quad*8+j][n=lane&15], C/D col=lane&15 row=quad*4+reg.
template<int K, int C, typename OutT, bool DOTS>
__global__ __launch_bounds__(256) void
gemm_mfma(const float* __restrict__ x, const _Float16* __restrict__ wt,
          const float* __restrict__ bias, OutT* __restrict__ out, int n,
          const float* __restrict__ scale, const float* __restrict__ shift,
          const float* __restrict__ a_s, const float* __restrict__ a_d,
          float* __restrict__ e_n, float* __restrict__ f_n) {
    constexpr int NW_C = C / 64;           // col groups per block (2 or 4)
    constexpr int RT   = NW_C;             // 16-row tiles per wave
    constexpr int LK   = K + 8;            // pad: keeps 16B alignment, spreads banks
    __shared__ _Float16 xs[64 * LK];
    __shared__ float ef_sh[2][64];
    const int row0 = blockIdx.x * 64;
    const int t = threadIdx.x;

    if (DOTS && t < 64) { ef_sh[0][t] = 0.f; ef_sh[1][t] = 0.f; }

    // stage 64 x K fp32 -> fp16 LDS (4 elems/thread/iter)
    for (int i = t * 4; i < 64 * K; i += 256 * 4) {
        int r = i / K, c = i - (i / K) * K;
        float4 v = make_float4(0.f, 0.f, 0.f, 0.f);
        if (row0 + r < n) v = *(const float4*)&x[(size_t)(row0 + r) * K + c];
        if (scale) {
            v.x = v.x * scale[c] + shift[c];         v.x = v.x > 0.f ? v.x : ACT_SLOPE * v.x;
            v.y = v.y * scale[c + 1] + shift[c + 1]; v.y = v.y > 0.f ? v.y : ACT_SLOPE * v.y;
            v.z = v.z * scale[c + 2] + shift[c + 2]; v.z = v.z > 0.f ? v.z : ACT_SLOPE * v.z;
            v.w = v.w * scale[c + 3] + shift[c + 3]; v.w = v.w > 0.f ? v.w : ACT_SLOPE * v.w;
        }
        half4_t h4 = { (_Float16)v.x, (_Float16)v.y, (_Float16)v.z, (_Float16)v.w };
        *(half4_t*)&xs[r * LK + c] = h4;
    }
    __syncthreads();

    const int w = t >> 6, l = t & 63;
    const int l16 = l & 15, quad = l >> 4;
    const int c0 = (w % NW_C) * 64;
    const int mbase = (w / NW_C) * (16 * NW_C);

    f32x4 acc[RT][4] = {};
    for (int k0 = 0; k0 < K; k0 += 32) {
        half8_t b[4];
#pragma unroll
        for (int tt = 0; tt < 4; ++tt)
            b[tt] = *(const half8_t*)&wt[(size_t)(c0 + tt * 16 + l16) * K + k0 + quad * 8];
        half8_t a[RT];
#pragma unroll
        for (int rt = 0; rt < RT; ++rt)
            a[rt] = *(const half8_t*)&xs[(mbase + rt * 16 + l16) * LK + k0 + quad * 8];
#pragma unroll
        for (int rt = 0; rt < RT; ++rt)
#pragma unroll
            for (int tt = 0; tt < 4; ++tt)
                acc[rt][tt] = __builtin_amdgcn_mfma_f32_16x16x32_f16(a[rt], b[tt],
                                                                     acc[rt][tt], 0, 0, 0);
    }

    // store + optional fused attention dots
#pragma unroll
    for (int rt = 0; rt < RT; ++rt) {
        int rb = row0 + mbase + rt * 16 + quad * 4;
#pragma unroll
        for (int tt = 0; tt < 4; ++tt) {
            int col = c0 + tt * 16 + l16;
            float bb = bias ? bias[col] : 0.f;
#pragma unroll
            for (int i = 0; i < 4; ++i)
                if (rb + i < n)
                    store_val(&out[(size_t)(rb + i) * C + col], acc[rt][tt][i] + bb);
        }
        if (DOTS) {
            float pe[4] = {0.f, 0.f, 0.f, 0.f}, pf[4] = {0.f, 0.f, 0.f, 0.f};
#pragma unroll
            for (int tt = 0; tt < 4; ++tt) {
                int col = c0 + tt * 16 + l16;
                float as_ = a_s[col], ad_ = a_d[col];
#pragma unroll
                for (int i = 0; i < 4; ++i) {
                    pe[i] += acc[rt][tt][i] * as_;
                    pf[i] += acc[rt][tt][i] * ad_;
                }
            }
#pragma unroll
            for (int m = 1; m < 16; m <<= 1)
#pragma unroll
                for (int i = 0; i < 4; ++i) {
                    pe[i] += __shfl_xor(pe[i], m, 64);
                    pf[i] += __shfl_xor(pf[i], m, 64);
                }
            if (l16 == 0) {
                int lr = mbase + rt * 16 + quad * 4;
#pragma unroll
                for (int i = 0; i < 4; ++i) {
                    atomicAdd(&ef_sh[0][lr + i], pe[i]);
                    atomicAdd(&ef_sh[1][lr + i], pf[i]);
                }
            }
        }
    }
    if (DOTS) {
        __syncthreads();
        if (t < 64 && row0 + t < n) {
            e_n[row0 + t] = ef_sh[0][t];
            f_n[row0 + t] = ef_sh[1][t];
        }
    }
}

// ---- CSR build over dst ----
__global__ void csr_count(const int* __restrict__ ei, int* __restrict__ cnt) {
    int e = blockIdx.x * blockDim.x + threadIdx.x;
    if (e >= N_TOT) return;
    int d = (e < N_EDGES) ? ei[N_EDGES + e] : (e - N_EDGES);
    atomicAdd(&cnt[d], 1);
}

__global__ void scan_phase1(const int* __restrict__ cnt, int* __restrict__ ptr,
                            int* __restrict__ tsum) {
    __shared__ int wsum[16];
    int base = blockIdx.x * SCAN_T;
    int t = threadIdx.x, lane = t & 63, w = t >> 6;
    int v = (base + t < N_NODES) ? cnt[base + t] : 0;
    int x = v;
#pragma unroll
    for (int off = 1; off < 64; off <<= 1) {
        int y = __shfl_up(x, off, 64);
        if (lane >= off) x += y;
    }
    if (lane == 63) wsum[w] = x;
    __syncthreads();
    if (t == 0) {
        int s = 0;
#pragma unroll
        for (int i = 0; i < 16; ++i) { int tmp = wsum[i]; wsum[i] = s; s += tmp; }
    }
    __syncthreads();
    int incl = x + wsum[w];
    if (base + t < N_NODES) ptr[base + t] = incl - v;
    if (t == SCAN_T - 1) tsum[blockIdx.x] = incl;
}

__global__ void scan_phase2(const int* __restrict__ tsum, int* __restrict__ toff,
                            int* __restrict__ ptr) {
    int t = threadIdx.x;
    int v = (t < N_TILES) ? tsum[t] : 0;
    int x = v;
#pragma unroll
    for (int off = 1; off < 64; off <<= 1) {
        int y = __shfl_up(x, off, 64);
        if (t >= off) x += y;
    }
    if (t < N_TILES) toff[t] = x - v;
    if (t == 63) ptr[N_NODES] = x;
}

__global__ void scan_phase3(int* __restrict__ ptr, const int* __restrict__ toff) {
    int i = blockIdx.x * SCAN_T + threadIdx.x;
    if (i < N_NODES) ptr[i] += toff[blockIdx.x];
}

__global__ void csr_fill_src(const int* __restrict__ ei, const int* __restrict__ ptr,
                             int* __restrict__ cur, int* __restrict__ srcs) {
    int e = blockIdx.x * blockDim.x + threadIdx.x;
    if (e >= N_TOT) return;
    int s, d;
    if (e < N_EDGES) { s = ei[e]; d = ei[N_EDGES + e]; }
    else { s = e - N_EDGES; d = s; }
    int pos = ptr[d] + atomicAdd(&cur[d], 1);
    srcs[pos] = s;
}

// ---- per-dst softmax weights, CSR order, pre-normalized. one wave per dst ----
__global__ void attn_w(const int* __restrict__ srcs, const int* __restrict__ ptr,
                       const float* __restrict__ e_n, const float* __restrict__ f_n,
                       float* __restrict__ wc) {
    int d = blockIdx.x * 4 + (threadIdx.x >> 6);
    int lane = threadIdx.x & 63;
    if (d >= N_NODES) return;
    int b0 = ptr[d], b1 = ptr[d + 1];
    float fd = f_n[d];
    float mymax = -1e30f;
    for (int j = b0 + lane; j < b1; j += 64) {
        float lg = e_n[srcs[j]] + fd;
        lg = lg > 0.f ? lg : GAT_SLOPE * lg;
        wc[j] = lg;
        mymax = fmaxf(mymax, lg);
    }
    float m = wred_max(mymax);
    float myden = 0.f;
    for (int j = b0 + lane; j < b1; j += 64) {
        float ex = __expf(wc[j] - m);
        wc[j] = ex;
        myden += ex;
    }
    float inv = 1.f / wred_sum(myden);
    for (int j = b0 + lane; j < b1; j += 64) wc[j] *= inv;
}

// ---- weighted gather aggregation, wave-per-dst, 16B/lane loads ----
// RL = C/8 lanes cover one row with half8; G = 64/RL rows per wave-instr;
// x2 manual unroll => 2G rows in flight per wave. 4 waves (4 dsts) per block.
template<int C>
__global__ __launch_bounds__(256) void
aggregate_w(const _Float16* __restrict__ h, const int* __restrict__ srcs,
            const float* __restrict__ wc, const int* __restrict__ ptr,
            const float* __restrict__ bias, float* __restrict__ out) {
    constexpr int RL = C / 8;          // 32 (C=256) or 16 (C=128)
    constexpr int G  = 64 / RL;        // 2 or 4
    int d = blockIdx.x * 4 + (threadIdx.x >> 6);
    if (d >= N_NODES) return;
    int l  = threadIdx.x & 63;
    int g  = l / RL;                   // row-group of this lane
    int cl = l % RL;                   // channel chunk within row
    int b0 = ptr[d], b1 = ptr[d + 1];
    float acc[8] = {0.f, 0.f, 0.f, 0.f, 0.f, 0.f, 0.f, 0.f};
    for (int j0 = b0; j0 < b1; j0 += 2 * G) {
        int j1 = j0 + g, j2 = j0 + G + g;
        float w1 = 0.f, w2 = 0.f;
        int s1 = 0, s2 = 0;
        if (j1 < b1) { w1 = wc[j1]; s1 = srcs[j1]; }
        if (j2 < b1) { w2 = wc[j2]; s2 = srcs[j2]; }
        half8_t v1 = *(const half8_t*)&h[(size_t)s1 * C + cl * 8];
        half8_t v2 = *(const half8_t*)&h[(size_t)s2 * C + cl * 8];
#pragma unroll
        for (int i = 0; i < 8; ++i)
            acc[i] += w1 * (float)v1[i] + w2 * (float)v2[i];
    }
#pragma unroll
    for (int m = RL; m < 64; m <<= 1)
#pragma unroll
        for (int i = 0; i < 8; ++i) acc[i] += __shfl_xor(acc[i], m, 64);
    if (g == 0) {
        int c = cl * 8;
        float4 o0, o1;
        o0.x = acc[0] + bias[c];     o0.y = acc[1] + bias[c + 1];
        o0.z = acc[2] + bias[c + 2]; o0.w = acc[3] + bias[c + 3];
        o1.x = acc[4] + bias[c + 4]; o1.y = acc[5] + bias[c + 5];
        o1.z = acc[6] + bias[c + 6]; o1.w = acc[7] + bias[c + 7];
        *(float4*)&out[(size_t)d * C + c] = o0;
        *(float4*)&out[(size_t)d * C + c + 4] = o1;
    }
}

// ---- BatchNorm stats + fused-coefficient computation ----
template<int C>
__global__ void bn_stats(const float* __restrict__ x, double* __restrict__ sum,
                         double* __restrict__ sumsq) {
    int t = threadIdx.x;
    double s = 0., q = 0.;
    for (int r = blockIdx.x; r < N_NODES; r += gridDim.x) {
        float v = x[(size_t)r * C + t];
        s += v;
        q += (double)v * v;
    }
    atomicAdd(&sum[t], s);
    atomicAdd(&sumsq[t], q);
}

template<int C>
__global__ void bn_coef(const double* __restrict__ sum, const double* __restrict__ sumsq,
                        const float* __restrict__ gamma, const float* __restrict__ beta,
                        float* __restrict__ scale, float* __restrict__ shift) {
    int c = threadIdx.x;
    float mu = (float)(sum[c] / N_NODES);
    float var = (float)(sumsq[c] / N_NODES) - mu * mu;
    float sc = gamma[c] * rsqrtf(var + EPS_BN);
    scale[c] = sc;
    shift[c] = beta[c] - mu * sc;
}

extern "C" void kernel_launch(void* const* d_in, const int* in_sizes, int n_in,
                              void* d_out, int out_size, void* d_ws, size_t ws_size,
                              hipStream_t stream) {
    const float* emb  = (const float*)d_in[0];
    const int*   ei   = (const int*)  d_in[1];
    const float* W1   = (const float*)d_in[2];
    const float* as1  = (const float*)d_in[3];
    const float* ad1  = (const float*)d_in[4];
    const float* b1   = (const float*)d_in[5];
    const float* g1   = (const float*)d_in[6];
    const float* be1  = (const float*)d_in[7];
    const float* W2   = (const float*)d_in[8];
    const float* as2  = (const float*)d_in[9];
    const float* ad2  = (const float*)d_in[10];
    const float* b2   = (const float*)d_in[11];
    const float* g2   = (const float*)d_in[12];
    const float* be2  = (const float*)d_in[13];
    const float* Wf   = (const float*)d_in[14];
    const float* bf   = (const float*)d_in[15];
    float* out = (float*)d_out;

    char* w = (char*)d_ws;
    auto alloc = [&](size_t bytes) {
        char* p = w;
        w += (bytes + 255) & ~(size_t)255;
        return (void*)p;
    };
    _Float16* hbuf = (_Float16*)alloc((size_t)N_NODES * 256 * 2); // h1/h2 fp16
    float*  x1   = (float*) alloc((size_t)N_NODES * 128 * 4);
    float*  e_n  = (float*) alloc((size_t)N_NODES * 4);
    float*  f_n  = (float*) alloc((size_t)N_NODES * 4);
    float*  wc   = (float*) alloc((size_t)N_TOT * 4);
    int*    srcs = (int*)   alloc((size_t)N_TOT * 4);
    int*    cnt  = (int*)   alloc((size_t)N_NODES * 4);
    int*    cur  = (int*)   alloc((size_t)N_NODES * 4);
    int*    ptr  = (int*)   alloc((size_t)(N_NODES + 1) * 4);
    int*    tsum = (int*)   alloc((size_t)N_TILES * 4);
    int*    toff = (int*)   alloc((size_t)N_TILES * 4);
    double* csum = (double*)alloc(256 * 8);
    double* csq  = (double*)alloc(256 * 8);
    float*  sc1  = (float*) alloc(128 * 4);
    float*  sh1  = (float*) alloc(128 * 4);
    float*  sc2  = (float*) alloc(256 * 4);
    float*  sh2  = (float*) alloc(256 * 4);
    _Float16* wt1 = (_Float16*)alloc((size_t)64 * 128 * 2);
    _Float16* wt2 = (_Float16*)alloc((size_t)128 * 256 * 2);
    _Float16* wtf = (_Float16*)alloc((size_t)256 * 256 * 2);

    const int EB   = (N_TOT + 255) / 256;
    const int GB64 = (N_NODES + 63) / 64;
    const int AW   = (N_NODES + 3) / 4;

    // ---- weight transpose+cast (small) ----
    wcast_t<64, 128><<<(64 * 128 + 255) / 256, 256, 0, stream>>>(W1, wt1);
    wcast_t<128, 256><<<(128 * 256 + 255) / 256, 256, 0, stream>>>(W2, wt2);
    wcast_t<256, 256><<<(256 * 256 + 255) / 256, 256, 0, stream>>>(Wf, wtf);

    // ---- CSR build (shared by both layers) ----
    hipMemsetAsync(cnt, 0, (size_t)N_NODES * 4, stream);
    hipMemsetAsync(cur, 0, (size_t)N_NODES * 4, stream);
    csr_count<<<EB, 256, 0, stream>>>(ei, cnt);
    scan_phase1<<<N_TILES, SCAN_T, 0, stream>>>(cnt, ptr, tsum);
    scan_phase2<<<1, 64, 0, stream>>>(tsum, toff, ptr);
    scan_phase3<<<N_TILES, SCAN_T, 0, stream>>>(ptr, toff);
    csr_fill_src<<<EB, 256, 0, stream>>>(ei, ptr, cur, srcs);

    // ---- Layer 1: 64 -> 128 (dots fused) ----
    gemm_mfma<64, 128, _Float16, true><<<GB64, 256, 0, stream>>>(
        emb, wt1, nullptr, hbuf, N_NODES, nullptr, nullptr, as1, ad1, e_n, f_n);
    attn_w<<<AW, 256, 0, stream>>>(srcs, ptr, e_n, f_n, wc);
    aggregate_w<128><<<AW, 256, 0, stream>>>(hbuf, srcs, wc, ptr, b1, x1);
    hipMemsetAsync(csum, 0, 256 * 8, stream);
    hipMemsetAsync(csq,  0, 256 * 8, stream);
    bn_stats<128><<<400, 128, 0, stream>>>(x1, csum, csq);
    bn_coef<128><<<1, 128, 0, stream>>>(csum, csq, g1, be1, sc1, sh1);

    // ---- Layer 2: 128 -> 256 (BN1+lrelu fused into staging, dots fused) ----
    gemm_mfma<128, 256, _Float16, true><<<GB64, 256, 0, stream>>>(
        x1, wt2, nullptr, hbuf, N_NODES, sc1, sh1, as2, ad2, e_n, f_n);
    attn_w<<<AW, 256, 0, stream>>>(srcs, ptr, e_n, f_n, wc);
    aggregate_w<256><<<AW, 256, 0, stream>>>(hbuf, srcs, wc, ptr, b2, out);
    hipMemsetAsync(csum, 0, 256 * 8, stream);
    hipMemsetAsync(csq,  0, 256 * 8, stream);
    bn_stats<256><<<400, 256, 0, stream>>>(out, csum, csq);
    bn_coef<256><<<1, 256, 0, stream>>>(csum, csq, g2, be2, sc2, sh2);

    // ---- Final linear 256 -> 256, in place, BN2+lrelu fused into staging ----
    gemm_mfma<256, 256, float, false><<<GB64, 256, 0, stream>>>(
        out, wtf, bf, out, N_NODES, sc2, sh2, nullptr, nullptr, nullptr, nullptr);
}

// Round 7
// 478.019 us; speedup vs baseline: 1.0929x; 1.0929x over previous
//
#include <hip/hip_runtime.h>
#include <hip/hip_fp16.h>
#include <math.h>

#define N_NODES 50000
#define N_EDGES 800000
#define N_TOT   850000   // E + N self-loops
#define EPS_BN  1e-5f
#define GAT_SLOPE 0.2f
#define ACT_SLOPE 0.01f
#define SCAN_T   1024
#define N_TILES  ((N_NODES + SCAN_T - 1) / SCAN_T)   // 49

typedef _Float16 half8_t __attribute__((ext_vector_type(8)));
typedef _Float16 half4_t __attribute__((ext_vector_type(4)));
typedef float    f32x4   __attribute__((ext_vector_type(4)));

__device__ __forceinline__ float wred_max(float x) {
#pragma unroll
    for (int m = 32; m; m >>= 1) x = fmaxf(x, __shfl_xor(x, m, 64));
    return x;
}
__device__ __forceinline__ float wred_sum(float x) {
#pragma unroll
    for (int m = 32; m; m >>= 1) x += __shfl_xor(x, m, 64);
    return x;
}

__device__ __forceinline__ void store_val(float* p, float v) { *p = v; }
__device__ __forceinline__ void store_val(_Float16* p, float v) { *p = (_Float16)v; }

// ---- transpose + fp16-cast of W[K x C] -> Wt[C x K] ----
template<int K, int C>
__global__ void wcast_t(const float* __restrict__ W, _Float16* __restrict__ wt) {
    int i = blockIdx.x * 256 + threadIdx.x;
    if (i >= K * C) return;
    int k = i / C, c = i - k * C;          // coalesced read of W
    wt[(size_t)c * K + k] = (_Float16)W[i];
}

// ---- MFMA GEMM: out[n x C] = act(bn(x))[n x K] @ W[K x C] (+bias) ----
// 256 thr = 4 waves; 64 rows/block. Wave -> 64-col group (w % (C/64)), loops
// over RT=C/64 row-tiles; B-frags loaded once per k0 and reused across RT
// tiles (4*RT independent MFMAs per step). Optional fused BN+LeakyReLU on
// input during staging. If DOTS: epilogue computes e=h.a_s, f=h.a_d via
// 16-lane shfl reduce + LDS accumulation (replaces node_dots kernel).
// Layouts (verified m89/m120): A[m=lane&15][k=quad*8+j],
// B[k=quad*8+j][n=lane&15], C/D col=lane&15 row=quad*4+reg.
template<int K, int C, typename OutT, bool DOTS>
__global__ __launch_bounds__(256) void
gemm_mfma(const float* __restrict__ x, const _Float16* __restrict__ wt,
          const float* __restrict__ bias, OutT* __restrict__ out, int n,
          const float* __restrict__ scale, const float* __restrict__ shift,
          const float* __restrict__ a_s, const float* __restrict__ a_d,
          float* __restrict__ e_n, float* __restrict__ f_n) {
    constexpr int NW_C = C / 64;           // col groups per block (2 or 4)
    constexpr int RT   = NW_C;             // 16-row tiles per wave
    constexpr int LK   = K + 8;            // pad: keeps 16B alignment, spreads banks
    __shared__ _Float16 xs[64 * LK];
    __shared__ float ef_sh[2][64];
    const int row0 = blockIdx.x * 64;
    const int t = threadIdx.x;

    if (DOTS && t < 64) { ef_sh[0][t] = 0.f; ef_sh[1][t] = 0.f; }

    // stage 64 x K fp32 -> fp16 LDS (4 elems/thread/iter)
    for (int i = t * 4; i < 64 * K; i += 256 * 4) {
        int r = i / K, c = i - (i / K) * K;
        float4 v = make_float4(0.f, 0.f, 0.f, 0.f);
        if (row0 + r < n) v = *(const float4*)&x[(size_t)(row0 + r) * K + c];
        if (scale) {
            v.x = v.x * scale[c] + shift[c];         v.x = v.x > 0.f ? v.x : ACT_SLOPE * v.x;
            v.y = v.y * scale[c + 1] + shift[c + 1]; v.y = v.y > 0.f ? v.y : ACT_SLOPE * v.y;
            v.z = v.z * scale[c + 2] + shift[c + 2]; v.z = v.z > 0.f ? v.z : ACT_SLOPE * v.z;
            v.w = v.w * scale[c + 3] + shift[c + 3]; v.w = v.w > 0.f ? v.w : ACT_SLOPE * v.w;
        }
        half4_t h4 = { (_Float16)v.x, (_Float16)v.y, (_Float16)v.z, (_Float16)v.w };
        *(half4_t*)&xs[r * LK + c] = h4;
    }
    __syncthreads();

    const int w = t >> 6, l = t & 63;
    const int l16 = l & 15, quad = l >> 4;
    const int c0 = (w % NW_C) * 64;
    const int mbase = (w / NW_C) * (16 * NW_C);

    f32x4 acc[RT][4] = {};
    for (int k0 = 0; k0 < K; k0 += 32) {
        half8_t b[4];
#pragma unroll
        for (int tt = 0; tt < 4; ++tt)
            b[tt] = *(const half8_t*)&wt[(size_t)(c0 + tt * 16 + l16) * K + k0 + quad * 8];
        half8_t a[RT];
#pragma unroll
        for (int rt = 0; rt < RT; ++rt)
            a[rt] = *(const half8_t*)&xs[(mbase + rt * 16 + l16) * LK + k0 + quad * 8];
#pragma unroll
        for (int rt = 0; rt < RT; ++rt)
#pragma unroll
            for (int tt = 0; tt < 4; ++tt)
                acc[rt][tt] = __builtin_amdgcn_mfma_f32_16x16x32_f16(a[rt], b[tt],
                                                                     acc[rt][tt], 0, 0, 0);
    }

    // store + optional fused attention dots
#pragma unroll
    for (int rt = 0; rt < RT; ++rt) {
        int rb = row0 + mbase + rt * 16 + quad * 4;
#pragma unroll
        for (int tt = 0; tt < 4; ++tt) {
            int col = c0 + tt * 16 + l16;
            float bb = bias ? bias[col] : 0.f;
#pragma unroll
            for (int i = 0; i < 4; ++i)
                if (rb + i < n)
                    store_val(&out[(size_t)(rb + i) * C + col], acc[rt][tt][i] + bb);
        }
        if (DOTS) {
            float pe[4] = {0.f, 0.f, 0.f, 0.f}, pf[4] = {0.f, 0.f, 0.f, 0.f};
#pragma unroll
            for (int tt = 0; tt < 4; ++tt) {
                int col = c0 + tt * 16 + l16;
                float as_ = a_s[col], ad_ = a_d[col];
#pragma unroll
                for (int i = 0; i < 4; ++i) {
                    pe[i] += acc[rt][tt][i] * as_;
                    pf[i] += acc[rt][tt][i] * ad_;
                }
            }
#pragma unroll
            for (int m = 1; m < 16; m <<= 1)
#pragma unroll
                for (int i = 0; i < 4; ++i) {
                    pe[i] += __shfl_xor(pe[i], m, 64);
                    pf[i] += __shfl_xor(pf[i], m, 64);
                }
            if (l16 == 0) {
                int lr = mbase + rt * 16 + quad * 4;
#pragma unroll
                for (int i = 0; i < 4; ++i) {
                    atomicAdd(&ef_sh[0][lr + i], pe[i]);
                    atomicAdd(&ef_sh[1][lr + i], pf[i]);
                }
            }
        }
    }
    if (DOTS) {
        __syncthreads();
        if (t < 64 && row0 + t < n) {
            e_n[row0 + t] = ef_sh[0][t];
            f_n[row0 + t] = ef_sh[1][t];
        }
    }
}

// ---- CSR build over dst ----
__global__ void csr_count(const int* __restrict__ ei, int* __restrict__ cnt) {
    int e = blockIdx.x * blockDim.x + threadIdx.x;
    if (e >= N_TOT) return;
    int d = (e < N_EDGES) ? ei[N_EDGES + e] : (e - N_EDGES);
    atomicAdd(&cnt[d], 1);
}

__global__ void scan_phase1(const int* __restrict__ cnt, int* __restrict__ ptr,
                            int* __restrict__ tsum) {
    __shared__ int wsum[16];
    int base = blockIdx.x * SCAN_T;
    int t = threadIdx.x, lane = t & 63, w = t >> 6;
    int v = (base + t < N_NODES) ? cnt[base + t] : 0;
    int x = v;
#pragma unroll
    for (int off = 1; off < 64; off <<= 1) {
        int y = __shfl_up(x, off, 64);
        if (lane >= off) x += y;
    }
    if (lane == 63) wsum[w] = x;
    __syncthreads();
    if (t == 0) {
        int s = 0;
#pragma unroll
        for (int i = 0; i < 16; ++i) { int tmp = wsum[i]; wsum[i] = s; s += tmp; }
    }
    __syncthreads();
    int incl = x + wsum[w];
    if (base + t < N_NODES) ptr[base + t] = incl - v;
    if (t == SCAN_T - 1) tsum[blockIdx.x] = incl;
}

__global__ void scan_phase2(const int* __restrict__ tsum, int* __restrict__ toff,
                            int* __restrict__ ptr) {
    int t = threadIdx.x;
    int v = (t < N_TILES) ? tsum[t] : 0;
    int x = v;
#pragma unroll
    for (int off = 1; off < 64; off <<= 1) {
        int y = __shfl_up(x, off, 64);
        if (t >= off) x += y;
    }
    if (t < N_TILES) toff[t] = x - v;
    if (t == 63) ptr[N_NODES] = x;
}

__global__ void scan_phase3(int* __restrict__ ptr, const int* __restrict__ toff) {
    int i = blockIdx.x * SCAN_T + threadIdx.x;
    if (i < N_NODES) ptr[i] += toff[blockIdx.x];
}

__global__ void csr_fill_src(const int* __restrict__ ei, const int* __restrict__ ptr,
                             int* __restrict__ cur, int* __restrict__ srcs) {
    int e = blockIdx.x * blockDim.x + threadIdx.x;
    if (e >= N_TOT) return;
    int s, d;
    if (e < N_EDGES) { s = ei[e]; d = ei[N_EDGES + e]; }
    else { s = e - N_EDGES; d = s; }
    int pos = ptr[d] + atomicAdd(&cur[d], 1);
    srcs[pos] = s;
}

// ---- fused softmax + weighted gather, wave-per-dst ----
// Pass 1: online softmax (m, den) over edges, gathering e_n[src] (L2-hot).
// Pass 2: per 64-edge chunk, each lane computes one pre-normalized weight;
// channel-parallel lanes pull weight+src via dynamic shfl (no LDS/barrier)
// and gather h rows with 16B loads. RL=C/8 lanes per row, G=64/RL rows per
// instr, x2 unroll. 4 waves (4 dsts) per block.
template<int C>
__global__ __launch_bounds__(256) void
attn_aggregate(const _Float16* __restrict__ h, const int* __restrict__ srcs,
               const int* __restrict__ ptr, const float* __restrict__ e_n,
               const float* __restrict__ f_n, const float* __restrict__ bias,
               float* __restrict__ out) {
    constexpr int RL = C / 8;          // 32 (C=256) or 16 (C=128)
    constexpr int G  = 64 / RL;        // 2 or 4
    int d = blockIdx.x * 4 + (threadIdx.x >> 6);
    if (d >= N_NODES) return;
    int l  = threadIdx.x & 63;
    int b0 = ptr[d], b1 = ptr[d + 1];
    float fd = f_n[d];

    // online softmax stats
    float m_l = -1e30f, den_l = 0.f;
    for (int j = b0 + l; j < b1; j += 64) {
        float lg = e_n[srcs[j]] + fd;
        lg = lg > 0.f ? lg : GAT_SLOPE * lg;
        float nm = fmaxf(m_l, lg);
        den_l = den_l * __expf(m_l - nm) + __expf(lg - nm);
        m_l = nm;
    }
    float m = wred_max(m_l);
    float inv = 1.f / wred_sum(den_l * __expf(m_l - m));

    int g  = l / RL;                   // row-group of this lane
    int cl = l % RL;                   // channel chunk within row
    float acc[8] = {0.f, 0.f, 0.f, 0.f, 0.f, 0.f, 0.f, 0.f};
    for (int c0 = b0; c0 < b1; c0 += 64) {
        int jl = c0 + l;
        int sj = 0; float ex = 0.f;
        if (jl < b1) {
            sj = srcs[jl];
            float lg = e_n[sj] + fd;
            lg = lg > 0.f ? lg : GAT_SLOPE * lg;
            ex = __expf(lg - m) * inv;
        }
        int nE = min(64, b1 - c0);
        for (int jj = 0; jj < nE; jj += 2 * G) {
            int j1 = jj + g, j2 = jj + G + g;        // always <= 63
            float w1 = __shfl(ex, j1, 64);
            int   s1 = __shfl(sj, j1, 64);
            float w2 = __shfl(ex, j2, 64);
            int   s2 = __shfl(sj, j2, 64);
            half8_t v1 = *(const half8_t*)&h[(size_t)s1 * C + cl * 8];
            half8_t v2 = *(const half8_t*)&h[(size_t)s2 * C + cl * 8];
#pragma unroll
            for (int i = 0; i < 8; ++i)
                acc[i] += w1 * (float)v1[i] + w2 * (float)v2[i];
        }
    }
#pragma unroll
    for (int mm = RL; mm < 64; mm <<= 1)
#pragma unroll
        for (int i = 0; i < 8; ++i) acc[i] += __shfl_xor(acc[i], mm, 64);
    if (g == 0) {
        int c = cl * 8;
        float4 o0, o1;
        o0.x = acc[0] + bias[c];     o0.y = acc[1] + bias[c + 1];
        o0.z = acc[2] + bias[c + 2]; o0.w = acc[3] + bias[c + 3];
        o1.x = acc[4] + bias[c + 4]; o1.y = acc[5] + bias[c + 5];
        o1.z = acc[6] + bias[c + 6]; o1.w = acc[7] + bias[c + 7];
        *(float4*)&out[(size_t)d * C + c] = o0;
        *(float4*)&out[(size_t)d * C + c + 4] = o1;
    }
}

// ---- BatchNorm stats + fused-coefficient computation ----
template<int C>
__global__ void bn_stats(const float* __restrict__ x, double* __restrict__ sum,
                         double* __restrict__ sumsq) {
    int t = threadIdx.x;
    double s = 0., q = 0.;
    for (int r = blockIdx.x; r < N_NODES; r += gridDim.x) {
        float v = x[(size_t)r * C + t];
        s += v;
        q += (double)v * v;
    }
    atomicAdd(&sum[t], s);
    atomicAdd(&sumsq[t], q);
}

template<int C>
__global__ void bn_coef(const double* __restrict__ sum, const double* __restrict__ sumsq,
                        const float* __restrict__ gamma, const float* __restrict__ beta,
                        float* __restrict__ scale, float* __restrict__ shift) {
    int c = threadIdx.x;
    float mu = (float)(sum[c] / N_NODES);
    float var = (float)(sumsq[c] / N_NODES) - mu * mu;
    float sc = gamma[c] * rsqrtf(var + EPS_BN);
    scale[c] = sc;
    shift[c] = beta[c] - mu * sc;
}

extern "C" void kernel_launch(void* const* d_in, const int* in_sizes, int n_in,
                              void* d_out, int out_size, void* d_ws, size_t ws_size,
                              hipStream_t stream) {
    const float* emb  = (const float*)d_in[0];
    const int*   ei   = (const int*)  d_in[1];
    const float* W1   = (const float*)d_in[2];
    const float* as1  = (const float*)d_in[3];
    const float* ad1  = (const float*)d_in[4];
    const float* b1   = (const float*)d_in[5];
    const float* g1   = (const float*)d_in[6];
    const float* be1  = (const float*)d_in[7];
    const float* W2   = (const float*)d_in[8];
    const float* as2  = (const float*)d_in[9];
    const float* ad2  = (const float*)d_in[10];
    const float* b2   = (const float*)d_in[11];
    const float* g2   = (const float*)d_in[12];
    const float* be2  = (const float*)d_in[13];
    const float* Wf   = (const float*)d_in[14];
    const float* bf   = (const float*)d_in[15];
    float* out = (float*)d_out;

    char* w = (char*)d_ws;
    auto alloc = [&](size_t bytes) {
        char* p = w;
        w += (bytes + 255) & ~(size_t)255;
        return (void*)p;
    };
    _Float16* hbuf = (_Float16*)alloc((size_t)N_NODES * 256 * 2); // h1/h2 fp16
    float*  x1   = (float*) alloc((size_t)N_NODES * 128 * 4);
    float*  e_n  = (float*) alloc((size_t)N_NODES * 4);
    float*  f_n  = (float*) alloc((size_t)N_NODES * 4);
    int*    srcs = (int*)   alloc((size_t)N_TOT * 4);
    int*    cnt  = (int*)   alloc((size_t)2 * N_NODES * 4);  // cnt | cur contiguous
    int*    cur  = cnt + N_NODES;
    int*    ptr  = (int*)   alloc((size_t)(N_NODES + 1) * 4);
    int*    tsum = (int*)   alloc((size_t)N_TILES * 4);
    int*    toff = (int*)   alloc((size_t)N_TILES * 4);
    double* csum = (double*)alloc((size_t)2 * 256 * 8);      // csum | csq contiguous
    double* csq  = csum + 256;
    float*  sc1  = (float*) alloc(128 * 4);
    float*  sh1  = (float*) alloc(128 * 4);
    float*  sc2  = (float*) alloc(256 * 4);
    float*  sh2  = (float*) alloc(256 * 4);
    _Float16* wt1 = (_Float16*)alloc((size_t)64 * 128 * 2);
    _Float16* wt2 = (_Float16*)alloc((size_t)128 * 256 * 2);
    _Float16* wtf = (_Float16*)alloc((size_t)256 * 256 * 2);

    const int EB   = (N_TOT + 255) / 256;
    const int GB64 = (N_NODES + 63) / 64;
    const int AW   = (N_NODES + 3) / 4;

    // ---- weight transpose+cast (small) ----
    wcast_t<64, 128><<<(64 * 128 + 255) / 256, 256, 0, stream>>>(W1, wt1);
    wcast_t<128, 256><<<(128 * 256 + 255) / 256, 256, 0, stream>>>(W2, wt2);
    wcast_t<256, 256><<<(256 * 256 + 255) / 256, 256, 0, stream>>>(Wf, wtf);

    // ---- CSR build (shared by both layers) ----
    hipMemsetAsync(cnt, 0, (size_t)2 * N_NODES * 4, stream);
    csr_count<<<EB, 256, 0, stream>>>(ei, cnt);
    scan_phase1<<<N_TILES, SCAN_T, 0, stream>>>(cnt, ptr, tsum);
    scan_phase2<<<1, 64, 0, stream>>>(tsum, toff, ptr);
    scan_phase3<<<N_TILES, SCAN_T, 0, stream>>>(ptr, toff);
    csr_fill_src<<<EB, 256, 0, stream>>>(ei, ptr, cur, srcs);

    // ---- Layer 1: 64 -> 128 (dots fused into GEMM, softmax fused into agg) ----
    gemm_mfma<64, 128, _Float16, true><<<GB64, 256, 0, stream>>>(
        emb, wt1, nullptr, hbuf, N_NODES, nullptr, nullptr, as1, ad1, e_n, f_n);
    attn_aggregate<128><<<AW, 256, 0, stream>>>(hbuf, srcs, ptr, e_n, f_n, b1, x1);
    hipMemsetAsync(csum, 0, (size_t)2 * 256 * 8, stream);
    bn_stats<128><<<400, 128, 0, stream>>>(x1, csum, csq);
    bn_coef<128><<<1, 128, 0, stream>>>(csum, csq, g1, be1, sc1, sh1);

    // ---- Layer 2: 128 -> 256 ----
    gemm_mfma<128, 256, _Float16, true><<<GB64, 256, 0, stream>>>(
        x1, wt2, nullptr, hbuf, N_NODES, sc1, sh1, as2, ad2, e_n, f_n);
    attn_aggregate<256><<<AW, 256, 0, stream>>>(hbuf, srcs, ptr, e_n, f_n, b2, out);
    hipMemsetAsync(csum, 0, (size_t)2 * 256 * 8, stream);
    bn_stats<256><<<400, 256, 0, stream>>>(out, csum, csq);
    bn_coef<256><<<1, 256, 0, stream>>>(csum, csq, g2, be2, sc2, sh2);

    // ---- Final linear 256 -> 256, in place, BN2+lrelu fused into staging ----
    gemm_mfma<256, 256, float, false><<<GB64, 256, 0, stream>>>(
        out, wtf, bf, out, N_NODES, sc2, sh2, nullptr, nullptr, nullptr, nullptr);
}

// Round 8
// 473.168 us; speedup vs baseline: 1.1041x; 1.0103x over previous
//
#include <hip/hip_runtime.h>
#include <hip/hip_fp16.h>
#include <math.h>

#define N_NODES 50000
#define N_EDGES 800000
#define N_TOT   850000   // E + N self-loops
#define EPS_BN  1e-5f
#define GAT_SLOPE 0.2f
#define ACT_SLOPE 0.01f
#define SCAN_T   1024
#define N_TILES  ((N_NODES + SCAN_T - 1) / SCAN_T)   // 49
#define BN_BLKS  400

typedef _Float16 half8_t __attribute__((ext_vector_type(8)));
typedef _Float16 half4_t __attribute__((ext_vector_type(4)));
typedef float    f32x4   __attribute__((ext_vector_type(4)));

__device__ __forceinline__ float wred_max(float x) {
#pragma unroll
    for (int m = 32; m; m >>= 1) x = fmaxf(x, __shfl_xor(x, m, 64));
    return x;
}
__device__ __forceinline__ float wred_sum(float x) {
#pragma unroll
    for (int m = 32; m; m >>= 1) x += __shfl_xor(x, m, 64);
    return x;
}

__device__ __forceinline__ void store_val(float* p, float v) { *p = v; }
__device__ __forceinline__ void store_val(_Float16* p, float v) { *p = (_Float16)v; }

// ---- one-shot init: W1/W2/Wf transpose+fp16 cast, plus cnt/cur zeroing ----
__global__ void init_misc(const float* __restrict__ W1, const float* __restrict__ W2,
                          const float* __restrict__ Wf, _Float16* __restrict__ wt1,
                          _Float16* __restrict__ wt2, _Float16* __restrict__ wtf,
                          int* __restrict__ cnt) {
    int i = blockIdx.x * 256 + threadIdx.x;
    if (i < 2 * N_NODES) cnt[i] = 0;
    if (i < 8192) {                                  // W1: 64x128
        int k = i >> 7, c = i & 127;
        wt1[c * 64 + k] = (_Float16)W1[i];
    } else if (i < 8192 + 32768) {                   // W2: 128x256
        int j = i - 8192, k = j >> 8, c = j & 255;
        wt2[c * 128 + k] = (_Float16)W2[j];
    } else if (i < 8192 + 32768 + 65536) {           // Wf: 256x256
        int j = i - 40960, k = j >> 8, c = j & 255;
        wtf[c * 256 + k] = (_Float16)Wf[j];
    }
}

// ---- MFMA GEMM: out[n x C] = act(bn(x))[n x K] @ W[K x C] (+bias) ----
// 256 thr = 4 waves; 64 rows/block. Wave -> 64-col group, RT=C/64 row-tiles;
// B-frags loaded once per k0, reused across RT tiles. InT float or fp16;
// optional fused BN scale/shift + LeakyReLU applied during staging.
// If DOTS: epilogue computes e=h.a_s, f=h.a_d (replaces node_dots kernel).
template<int K, int C, typename InT, typename OutT, bool DOTS>
__global__ __launch_bounds__(256) void
gemm_mfma(const InT* __restrict__ x, const _Float16* __restrict__ wt,
          const float* __restrict__ bias, OutT* __restrict__ out, int n,
          const float* __restrict__ scale, const float* __restrict__ shift,
          const float* __restrict__ a_s, const float* __restrict__ a_d,
          float* __restrict__ e_n, float* __restrict__ f_n) {
    constexpr int NW_C = C / 64;
    constexpr int RT   = NW_C;
    constexpr int LK   = K + 8;
    __shared__ _Float16 xs[64 * LK];
    __shared__ float ef_sh[2][64];
    const int row0 = blockIdx.x * 64;
    const int t = threadIdx.x;

    if (DOTS && t < 64) { ef_sh[0][t] = 0.f; ef_sh[1][t] = 0.f; }

    if constexpr (__is_same(InT, _Float16)) {
        // 8 halves (16B) per thread per iter
        for (int i = t * 8; i < 64 * K; i += 256 * 8) {
            int r = i / K, c = i - (i / K) * K;
            half8_t v = {};
            if (row0 + r < n) v = *(const half8_t*)&x[(size_t)(row0 + r) * K + c];
            if (scale) {
#pragma unroll
                for (int j = 0; j < 8; ++j) {
                    float f = (float)v[j] * scale[c + j] + shift[c + j];
                    v[j] = (_Float16)(f > 0.f ? f : ACT_SLOPE * f);
                }
            }
            *(half8_t*)&xs[r * LK + c] = v;
        }
    } else {
        for (int i = t * 4; i < 64 * K; i += 256 * 4) {
            int r = i / K, c = i - (i / K) * K;
            float4 v = make_float4(0.f, 0.f, 0.f, 0.f);
            if (row0 + r < n) v = *(const float4*)&x[(size_t)(row0 + r) * K + c];
            if (scale) {
                v.x = v.x * scale[c] + shift[c];         v.x = v.x > 0.f ? v.x : ACT_SLOPE * v.x;
                v.y = v.y * scale[c + 1] + shift[c + 1]; v.y = v.y > 0.f ? v.y : ACT_SLOPE * v.y;
                v.z = v.z * scale[c + 2] + shift[c + 2]; v.z = v.z > 0.f ? v.z : ACT_SLOPE * v.z;
                v.w = v.w * scale[c + 3] + shift[c + 3]; v.w = v.w > 0.f ? v.w : ACT_SLOPE * v.w;
            }
            half4_t h4 = { (_Float16)v.x, (_Float16)v.y, (_Float16)v.z, (_Float16)v.w };
            *(half4_t*)&xs[r * LK + c] = h4;
        }
    }
    __syncthreads();

    const int w = t >> 6, l = t & 63;
    const int l16 = l & 15, quad = l >> 4;
    const int c0 = (w % NW_C) * 64;
    const int mbase = (w / NW_C) * (16 * NW_C);

    f32x4 acc[RT][4] = {};
    for (int k0 = 0; k0 < K; k0 += 32) {
        half8_t b[4];
#pragma unroll
        for (int tt = 0; tt < 4; ++tt)
            b[tt] = *(const half8_t*)&wt[(size_t)(c0 + tt * 16 + l16) * K + k0 + quad * 8];
        half8_t a[RT];
#pragma unroll
        for (int rt = 0; rt < RT; ++rt)
            a[rt] = *(const half8_t*)&xs[(mbase + rt * 16 + l16) * LK + k0 + quad * 8];
#pragma unroll
        for (int rt = 0; rt < RT; ++rt)
#pragma unroll
            for (int tt = 0; tt < 4; ++tt)
                acc[rt][tt] = __builtin_amdgcn_mfma_f32_16x16x32_f16(a[rt], b[tt],
                                                                     acc[rt][tt], 0, 0, 0);
    }

#pragma unroll
    for (int rt = 0; rt < RT; ++rt) {
        int rb = row0 + mbase + rt * 16 + quad * 4;
#pragma unroll
        for (int tt = 0; tt < 4; ++tt) {
            int col = c0 + tt * 16 + l16;
            float bb = bias ? bias[col] : 0.f;
#pragma unroll
            for (int i = 0; i < 4; ++i)
                if (rb + i < n)
                    store_val(&out[(size_t)(rb + i) * C + col], acc[rt][tt][i] + bb);
        }
        if (DOTS) {
            float pe[4] = {0.f, 0.f, 0.f, 0.f}, pf[4] = {0.f, 0.f, 0.f, 0.f};
#pragma unroll
            for (int tt = 0; tt < 4; ++tt) {
                int col = c0 + tt * 16 + l16;
                float as_ = a_s[col], ad_ = a_d[col];
#pragma unroll
                for (int i = 0; i < 4; ++i) {
                    pe[i] += acc[rt][tt][i] * as_;
                    pf[i] += acc[rt][tt][i] * ad_;
                }
            }
#pragma unroll
            for (int m = 1; m < 16; m <<= 1)
#pragma unroll
                for (int i = 0; i < 4; ++i) {
                    pe[i] += __shfl_xor(pe[i], m, 64);
                    pf[i] += __shfl_xor(pf[i], m, 64);
                }
            if (l16 == 0) {
                int lr = mbase + rt * 16 + quad * 4;
#pragma unroll
                for (int i = 0; i < 4; ++i) {
                    atomicAdd(&ef_sh[0][lr + i], pe[i]);
                    atomicAdd(&ef_sh[1][lr + i], pf[i]);
                }
            }
        }
    }
    if (DOTS) {
        __syncthreads();
        if (t < 64 && row0 + t < n) {
            e_n[row0 + t] = ef_sh[0][t];
            f_n[row0 + t] = ef_sh[1][t];
        }
    }
}

// ---- CSR build over dst ----
__global__ void csr_count(const int* __restrict__ ei, int* __restrict__ cnt) {
    int e = blockIdx.x * blockDim.x + threadIdx.x;
    if (e >= N_TOT) return;
    int d = (e < N_EDGES) ? ei[N_EDGES + e] : (e - N_EDGES);
    atomicAdd(&cnt[d], 1);
}

__global__ void scan_phase1(const int* __restrict__ cnt, int* __restrict__ ptr,
                            int* __restrict__ tsum) {
    __shared__ int wsum[16];
    int base = blockIdx.x * SCAN_T;
    int t = threadIdx.x, lane = t & 63, w = t >> 6;
    int v = (base + t < N_NODES) ? cnt[base + t] : 0;
    int x = v;
#pragma unroll
    for (int off = 1; off < 64; off <<= 1) {
        int y = __shfl_up(x, off, 64);
        if (lane >= off) x += y;
    }
    if (lane == 63) wsum[w] = x;
    __syncthreads();
    if (t == 0) {
        int s = 0;
#pragma unroll
        for (int i = 0; i < 16; ++i) { int tmp = wsum[i]; wsum[i] = s; s += tmp; }
    }
    __syncthreads();
    int incl = x + wsum[w];
    if (base + t < N_NODES) ptr[base + t] = incl - v;
    if (t == SCAN_T - 1) tsum[blockIdx.x] = incl;
}

__global__ void scan_phase2(const int* __restrict__ tsum, int* __restrict__ toff,
                            int* __restrict__ ptr) {
    int t = threadIdx.x;
    int v = (t < N_TILES) ? tsum[t] : 0;
    int x = v;
#pragma unroll
    for (int off = 1; off < 64; off <<= 1) {
        int y = __shfl_up(x, off, 64);
        if (t >= off) x += y;
    }
    if (t < N_TILES) toff[t] = x - v;
    if (t == 63) ptr[N_NODES] = x;
}

__global__ void scan_phase3(int* __restrict__ ptr, const int* __restrict__ toff) {
    int i = blockIdx.x * SCAN_T + threadIdx.x;
    if (i < N_NODES) ptr[i] += toff[blockIdx.x];
}

__global__ void csr_fill_src(const int* __restrict__ ei, const int* __restrict__ ptr,
                             int* __restrict__ cur, int* __restrict__ srcs) {
    int e = blockIdx.x * blockDim.x + threadIdx.x;
    if (e >= N_TOT) return;
    int s, d;
    if (e < N_EDGES) { s = ei[e]; d = ei[N_EDGES + e]; }
    else { s = e - N_EDGES; d = s; }
    int pos = ptr[d] + atomicAdd(&cur[d], 1);
    srcs[pos] = s;
}

// ---- fused softmax + weighted gather, wave-per-dst, fp16 output ----
template<int C>
__global__ __launch_bounds__(256) void
attn_aggregate(const _Float16* __restrict__ h, const int* __restrict__ srcs,
               const int* __restrict__ ptr, const float* __restrict__ e_n,
               const float* __restrict__ f_n, const float* __restrict__ bias,
               _Float16* __restrict__ out) {
    constexpr int RL = C / 8;          // 32 (C=256) or 16 (C=128)
    constexpr int G  = 64 / RL;        // 2 or 4
    int d = blockIdx.x * 4 + (threadIdx.x >> 6);
    if (d >= N_NODES) return;
    int l  = threadIdx.x & 63;
    int b0 = ptr[d], b1 = ptr[d + 1];
    float fd = f_n[d];

    // online softmax stats
    float m_l = -1e30f, den_l = 0.f;
    for (int j = b0 + l; j < b1; j += 64) {
        float lg = e_n[srcs[j]] + fd;
        lg = lg > 0.f ? lg : GAT_SLOPE * lg;
        float nm = fmaxf(m_l, lg);
        den_l = den_l * __expf(m_l - nm) + __expf(lg - nm);
        m_l = nm;
    }
    float m = wred_max(m_l);
    float inv = 1.f / wred_sum(den_l * __expf(m_l - m));

    int g  = l / RL;
    int cl = l % RL;
    float acc[8] = {0.f, 0.f, 0.f, 0.f, 0.f, 0.f, 0.f, 0.f};
    for (int c0 = b0; c0 < b1; c0 += 64) {
        int jl = c0 + l;
        int sj = 0; float ex = 0.f;
        if (jl < b1) {
            sj = srcs[jl];
            float lg = e_n[sj] + fd;
            lg = lg > 0.f ? lg : GAT_SLOPE * lg;
            ex = __expf(lg - m) * inv;
        }
        int nE = min(64, b1 - c0);
        for (int jj = 0; jj < nE; jj += 2 * G) {
            int j1 = jj + g, j2 = jj + G + g;
            float w1 = __shfl(ex, j1, 64);
            int   s1 = __shfl(sj, j1, 64);
            float w2 = __shfl(ex, j2, 64);
            int   s2 = __shfl(sj, j2, 64);
            half8_t v1 = *(const half8_t*)&h[(size_t)s1 * C + cl * 8];
            half8_t v2 = *(const half8_t*)&h[(size_t)s2 * C + cl * 8];
#pragma unroll
            for (int i = 0; i < 8; ++i)
                acc[i] += w1 * (float)v1[i] + w2 * (float)v2[i];
        }
    }
#pragma unroll
    for (int mm = RL; mm < 64; mm <<= 1)
#pragma unroll
        for (int i = 0; i < 8; ++i) acc[i] += __shfl_xor(acc[i], mm, 64);
    if (g == 0) {
        int c = cl * 8;
        half8_t o;
#pragma unroll
        for (int i = 0; i < 8; ++i) o[i] = (_Float16)(acc[i] + bias[c + i]);
        *(half8_t*)&out[(size_t)d * C + c] = o;
    }
}

// ---- BatchNorm stats from fp16 input: per-block partials (no atomics) ----
// C/2 threads; each owns a column pair (half2 loads). partial[blk*C + c] = (sum, sumsq)
template<int C>
__global__ void bn_stats_h(const _Float16* __restrict__ x, float2* __restrict__ partial) {
    int t = threadIdx.x;                 // 0 .. C/2-1
    float s0 = 0.f, q0 = 0.f, s1 = 0.f, q1 = 0.f;
    for (int r = blockIdx.x; r < N_NODES; r += gridDim.x) {
        __half2 hv = *(const __half2*)&x[(size_t)r * C + 2 * t];
        float2 v = __half22float2(hv);
        s0 += v.x; q0 += v.x * v.x;
        s1 += v.y; q1 += v.y * v.y;
    }
    partial[(size_t)blockIdx.x * C + 2 * t]     = make_float2(s0, q0);
    partial[(size_t)blockIdx.x * C + 2 * t + 1] = make_float2(s1, q1);
}

// reduce partials -> per-column scale/shift (C threads, 1 block)
template<int C>
__global__ void bn_coef(const float2* __restrict__ partial, const float* __restrict__ gamma,
                        const float* __restrict__ beta, float* __restrict__ scale,
                        float* __restrict__ shift) {
    int c = threadIdx.x;
    double s = 0., q = 0.;
    for (int b = 0; b < BN_BLKS; ++b) {
        float2 p = partial[(size_t)b * C + c];
        s += p.x; q += p.y;
    }
    float mu = (float)(s / N_NODES);
    float var = (float)(q / N_NODES) - mu * mu;
    float sc = gamma[c] * rsqrtf(var + EPS_BN);
    scale[c] = sc;
    shift[c] = beta[c] - mu * sc;
}

extern "C" void kernel_launch(void* const* d_in, const int* in_sizes, int n_in,
                              void* d_out, int out_size, void* d_ws, size_t ws_size,
                              hipStream_t stream) {
    const float* emb  = (const float*)d_in[0];
    const int*   ei   = (const int*)  d_in[1];
    const float* W1   = (const float*)d_in[2];
    const float* as1  = (const float*)d_in[3];
    const float* ad1  = (const float*)d_in[4];
    const float* b1   = (const float*)d_in[5];
    const float* g1   = (const float*)d_in[6];
    const float* be1  = (const float*)d_in[7];
    const float* W2   = (const float*)d_in[8];
    const float* as2  = (const float*)d_in[9];
    const float* ad2  = (const float*)d_in[10];
    const float* b2   = (const float*)d_in[11];
    const float* g2   = (const float*)d_in[12];
    const float* be2  = (const float*)d_in[13];
    const float* Wf   = (const float*)d_in[14];
    const float* bf   = (const float*)d_in[15];
    float* out = (float*)d_out;

    char* w = (char*)d_ws;
    auto alloc = [&](size_t bytes) {
        char* p = w;
        w += (bytes + 255) & ~(size_t)255;
        return (void*)p;
    };
    _Float16* hbuf  = (_Float16*)alloc((size_t)N_NODES * 256 * 2); // h1/h2 fp16
    _Float16* x1h   = (_Float16*)alloc((size_t)N_NODES * 128 * 2); // agg1 out fp16
    _Float16* x2h   = (_Float16*)alloc((size_t)N_NODES * 256 * 2); // agg2 out fp16
    float*  e_n  = (float*) alloc((size_t)N_NODES * 4);
    float*  f_n  = (float*) alloc((size_t)N_NODES * 4);
    int*    srcs = (int*)   alloc((size_t)N_TOT * 4);
    int*    cnt  = (int*)   alloc((size_t)2 * N_NODES * 4);  // cnt | cur contiguous
    int*    cur  = cnt + N_NODES;
    int*    ptr  = (int*)   alloc((size_t)(N_NODES + 1) * 4);
    int*    tsum = (int*)   alloc((size_t)N_TILES * 4);
    int*    toff = (int*)   alloc((size_t)N_TILES * 4);
    float2* pbn  = (float2*)alloc((size_t)BN_BLKS * 256 * 8);
    float*  sc1  = (float*) alloc(128 * 4);
    float*  sh1  = (float*) alloc(128 * 4);
    float*  sc2  = (float*) alloc(256 * 4);
    float*  sh2  = (float*) alloc(256 * 4);
    _Float16* wt1 = (_Float16*)alloc((size_t)64 * 128 * 2);
    _Float16* wt2 = (_Float16*)alloc((size_t)128 * 256 * 2);
    _Float16* wtf = (_Float16*)alloc((size_t)256 * 256 * 2);

    const int EB   = (N_TOT + 255) / 256;
    const int GB64 = (N_NODES + 63) / 64;
    const int AW   = (N_NODES + 3) / 4;

    // ---- init: weight transposes + cnt/cur zero (one dispatch) ----
    init_misc<<<(8192 + 32768 + 65536 + 255) / 256, 256, 0, stream>>>(
        W1, W2, Wf, wt1, wt2, wtf, cnt);

    // ---- CSR build (shared by both layers) ----
    csr_count<<<EB, 256, 0, stream>>>(ei, cnt);
    scan_phase1<<<N_TILES, SCAN_T, 0, stream>>>(cnt, ptr, tsum);
    scan_phase2<<<1, 64, 0, stream>>>(tsum, toff, ptr);
    scan_phase3<<<N_TILES, SCAN_T, 0, stream>>>(ptr, toff);
    csr_fill_src<<<EB, 256, 0, stream>>>(ei, ptr, cur, srcs);

    // ---- Layer 1: 64 -> 128 ----
    gemm_mfma<64, 128, float, _Float16, true><<<GB64, 256, 0, stream>>>(
        emb, wt1, nullptr, hbuf, N_NODES, nullptr, nullptr, as1, ad1, e_n, f_n);
    attn_aggregate<128><<<AW, 256, 0, stream>>>(hbuf, srcs, ptr, e_n, f_n, b1, x1h);
    bn_stats_h<128><<<BN_BLKS, 64, 0, stream>>>(x1h, pbn);
    bn_coef<128><<<1, 128, 0, stream>>>(pbn, g1, be1, sc1, sh1);

    // ---- Layer 2: 128 -> 256 (BN1+lrelu fused into staging) ----
    gemm_mfma<128, 256, _Float16, _Float16, true><<<GB64, 256, 0, stream>>>(
        x1h, wt2, nullptr, hbuf, N_NODES, sc1, sh1, as2, ad2, e_n, f_n);
    attn_aggregate<256><<<AW, 256, 0, stream>>>(hbuf, srcs, ptr, e_n, f_n, b2, x2h);
    bn_stats_h<256><<<BN_BLKS, 128, 0, stream>>>(x2h, pbn);
    bn_coef<256><<<1, 256, 0, stream>>>(pbn, g2, be2, sc2, sh2);

    // ---- Final linear 256 -> 256 (BN2+lrelu fused into staging) ----
    gemm_mfma<256, 256, _Float16, float, false><<<GB64, 256, 0, stream>>>(
        x2h, wtf, bf, out, N_NODES, sc2, sh2, nullptr, nullptr, nullptr, nullptr);
}